// Round 9
// baseline (185.474 us; speedup 1.0000x reference)
//
#include <hip/hip_runtime.h>
#include <hip/hip_bf16.h>
#include <math.h>

// ---------------------------------------------------------------------------
// EdgeAwareAttention: B=1, N=50000, D=128, H=8, d=16, E=800000
//  prep         : Wq,Wk,Wv,Wo f32->bf16
//  qkv_histfill : [blocks 0..EB4)  bucket CSR build, 4 edges/thread (MLP),
//                                  cnt padded to 64B/counter
//                 [blocks EB4..)   MFMA QKV (2 row-tiles/wave, batched B-loads)
//  edge_attn    : wave-per-node, bucket preloaded to regs + shfl distribution,
//                 lane=(slot,head), defer-max, slot-merge via shfl_xor
//  wo_ln        : MFMA Wo GEMM + residual + LayerNorm fused -> d_out
// Bucket capacity 64: deg~Poisson(16), P(deg>64)~1e-26; r<64 clamp = safe.
// ---------------------------------------------------------------------------

#define CAP 64

typedef __attribute__((ext_vector_type(8))) short short8;
typedef __attribute__((ext_vector_type(4))) float f32x4;

static __device__ __forceinline__ ushort f2bf(float f) {
  unsigned u = __float_as_uint(f);
  u += 0x7fff + ((u >> 16) & 1);          // RNE
  return (ushort)(u >> 16);
}
static __device__ __forceinline__ float bflo(unsigned u) {   // low bf16 -> f32
  return __uint_as_float(u << 16);
}
static __device__ __forceinline__ float bfhi(unsigned u) {   // high bf16 -> f32
  return __uint_as_float(u & 0xffff0000u);
}

// W convert (4*16384 f32 -> bf16)
__global__ __launch_bounds__(256) void prep_kernel(
    const float* __restrict__ Wq, const float* __restrict__ Wk,
    const float* __restrict__ Wv, const float* __restrict__ Wo,
    ushort* __restrict__ Wb) {
  int tid = blockIdx.x * 256 + threadIdx.x;
  if (tid < 16384) {
    int i = tid * 4;
    const float* src = (i < 16384) ? Wq : (i < 32768) ? Wk : (i < 49152) ? Wv : Wo;
    int off = i & 16383;
    float4 v = *(const float4*)(src + off);
    *(ushort4*)(Wb + i) = make_ushort4(f2bf(v.x), f2bf(v.y), f2bf(v.z), f2bf(v.w));
  }
}

// Fused: bucket CSR build (blocks < EB4, dispatched FIRST) | QKV MFMA GEMM.
// cnt stride 16 ints (one counter per 64B line).
// recs[s*CAP + r] = dst<<15 | (bf16(ew) & 0x7fff)
// KVb layout: row n = [K[0..128) | V[0..128)] (256 ushorts).
__global__ __launch_bounds__(256) void qkv_histfill_kernel(
    const float* __restrict__ x, const ushort* __restrict__ Wb,   // Wb: [3][128][128]
    float* __restrict__ Qf, ushort* __restrict__ KVb,
    const int* __restrict__ ei, const float* __restrict__ ew,
    int* __restrict__ cnt, unsigned* __restrict__ recs,
    int N, int E, int EB4) {
  if ((int)blockIdx.x < EB4) {
    int e0 = (int)blockIdx.x * 1024 + threadIdx.x * 4;
    if (e0 < E) {                           // E % 4 == 0: whole quad valid
      int4   ss = *(const int4*)(ei + e0);
      int4   dd = *(const int4*)(ei + E + e0);
      float4 ww = *(const float4*)(ew + e0);
      int r0 = atomicAdd(&cnt[ss.x << 4], 1);
      int r1 = atomicAdd(&cnt[ss.y << 4], 1);
      int r2 = atomicAdd(&cnt[ss.z << 4], 1);
      int r3 = atomicAdd(&cnt[ss.w << 4], 1);
      if (r0 < CAP) recs[((size_t)ss.x << 6) + r0] = ((unsigned)dd.x << 15) | ((unsigned)f2bf(ww.x) & 0x7fffu);
      if (r1 < CAP) recs[((size_t)ss.y << 6) + r1] = ((unsigned)dd.y << 15) | ((unsigned)f2bf(ww.y) & 0x7fffu);
      if (r2 < CAP) recs[((size_t)ss.z << 6) + r2] = ((unsigned)dd.z << 15) | ((unsigned)f2bf(ww.z) & 0x7fffu);
      if (r3 < CAP) recs[((size_t)ss.w << 6) + r3] = ((unsigned)dd.w << 15) | ((unsigned)f2bf(ww.w) & 0x7fffu);
    }
    return;
  }
  int bid = (int)blockIdx.x - EB4;
  int w = threadIdx.x >> 6, l = threadIdx.x & 63;
  int n0 = bid * 128 + w * 32;
  int lr = l & 15, lg = l >> 4;

  short8 a[2][4];
#pragma unroll
  for (int rt = 0; rt < 2; rt++) {
    int arow = n0 + rt * 16 + lr;
    if (arow < N) {
      const float* xrow = x + (size_t)arow * 128 + 8 * lg;
      float4 x0[4], x1[4];
#pragma unroll
      for (int ks = 0; ks < 4; ks++) {
        x0[ks] = *(const float4*)(xrow + 32 * ks);
        x1[ks] = *(const float4*)(xrow + 32 * ks + 4);
      }
#pragma unroll
      for (int ks = 0; ks < 4; ks++) {
        short8 t;
        t[0] = f2bf(x0[ks].x); t[1] = f2bf(x0[ks].y); t[2] = f2bf(x0[ks].z); t[3] = f2bf(x0[ks].w);
        t[4] = f2bf(x1[ks].x); t[5] = f2bf(x1[ks].y); t[6] = f2bf(x1[ks].z); t[7] = f2bf(x1[ks].w);
        a[rt][ks] = t;
      }
    } else {
#pragma unroll
      for (int ks = 0; ks < 4; ks++) a[rt][ks] = (short8){0,0,0,0,0,0,0,0};
    }
  }

  bool ok[2][4];
#pragma unroll
  for (int rt = 0; rt < 2; rt++)
#pragma unroll
    for (int r = 0; r < 4; r++) ok[rt][r] = (n0 + rt * 16 + 4 * lg + r) < N;

#pragma unroll
  for (int m = 0; m < 3; m++) {
    const ushort* Wm = Wb + m * 16384;
#pragma unroll
    for (int ctp = 0; ctp < 4; ctp++) {
      short8 b[2][4];
#pragma unroll
      for (int ci = 0; ci < 2; ci++) {
        const ushort* wrow = Wm + (size_t)((ctp * 2 + ci) * 16 + lr) * 128 + 8 * lg;
#pragma unroll
        for (int ks = 0; ks < 4; ks++) b[ci][ks] = *(const short8*)(wrow + 32 * ks);
      }
      f32x4 acc[2][2];
#pragma unroll
      for (int rt = 0; rt < 2; rt++)
#pragma unroll
        for (int ci = 0; ci < 2; ci++) {
          acc[rt][ci] = (f32x4){0.f, 0.f, 0.f, 0.f};
#pragma unroll
          for (int ks = 0; ks < 4; ks++)
            acc[rt][ci] = __builtin_amdgcn_mfma_f32_16x16x32_bf16(a[rt][ks], b[ci][ks], acc[rt][ci], 0, 0, 0);
        }
#pragma unroll
      for (int rt = 0; rt < 2; rt++)
#pragma unroll
        for (int ci = 0; ci < 2; ci++) {
          int c = (ctp * 2 + ci) * 16 + lr;
#pragma unroll
          for (int r = 0; r < 4; r++) {
            if (ok[rt][r]) {
              size_t row = (size_t)(n0 + rt * 16 + 4 * lg + r);
              if (m == 0)      Qf[row * 128 + c] = acc[rt][ci][r];
              else if (m == 1) KVb[row * 256 + c] = f2bf(acc[rt][ci][r]);
              else             KVb[row * 256 + 128 + c] = f2bf(acc[rt][ci][r]);
            }
          }
        }
    }
  }
}

// Wave-per-node: 64-thread block, lane = (slot u = l>>3, head h = l&7).
// Bucket preloaded: lane l holds rb[min(l,deg-1)]; per-iter rec via shfl.
// Per-lane online softmax chain (defer-max THR=8); slot-merge via shfl_xor.
__global__ __launch_bounds__(64) void edge_attn_kernel(
    const float* __restrict__ Qf, const ushort* __restrict__ KVb,
    const unsigned* __restrict__ recs, const float* __restrict__ We,
    const int* __restrict__ cnt, ushort* __restrict__ AGGb, int N) {
  int n = blockIdx.x;
  int l = threadIdx.x;
  int u = l >> 3, h = l & 7;
  int deg = min(cnt[n << 4], CAP);
  ushort* op = AGGb + (size_t)n * 128 + (h << 4);

  if (deg <= 0) {                    // no edges: agg = 0
    if (u == 0) {
      *(uint4*)(op + 0) = make_uint4(0, 0, 0, 0);
      *(uint4*)(op + 8) = make_uint4(0, 0, 0, 0);
    }
    return;
  }

  const unsigned* rb = recs + ((size_t)n << 6);
  unsigned myrec = rb[min(l, deg - 1)];          // coalesced bucket preload

  float q[16];
  const float* qp = Qf + (size_t)n * 128 + (h << 4);
  *(float4*)(q + 0)  = *(const float4*)(qp + 0);
  *(float4*)(q + 4)  = *(const float4*)(qp + 4);
  *(float4*)(q + 8)  = *(const float4*)(qp + 8);
  *(float4*)(q + 12) = *(const float4*)(qp + 12);
  float weh = We[h];

  float m = -INFINITY, de = 0.f;
  float acc[16];
#pragma unroll
  for (int d = 0; d < 16; d++) acc[d] = 0.f;

  for (int base = 0; base < deg; base += 8) {
    int idx = base + u;                          // <= 63
    unsigned rec = __shfl(myrec, idx);           // lanes >= deg hold rb[deg-1]
    const ushort* kv = KVb + (((rec >> 15) << 8) + (h << 4));
    uint4 k0 = *(const uint4*)kv;
    uint4 k1 = *(const uint4*)(kv + 8);
    uint4 v0 = *(const uint4*)(kv + 128);
    uint4 v1 = *(const uint4*)(kv + 136);

    float s;
    s  = q[0]  * bflo(k0.x) + q[1]  * bfhi(k0.x);
    s += q[2]  * bflo(k0.y) + q[3]  * bfhi(k0.y);
    s += q[4]  * bflo(k0.z) + q[5]  * bfhi(k0.z);
    s += q[6]  * bflo(k0.w) + q[7]  * bfhi(k0.w);
    s += q[8]  * bflo(k1.x) + q[9]  * bfhi(k1.x);
    s += q[10] * bflo(k1.y) + q[11] * bfhi(k1.y);
    s += q[12] * bflo(k1.z) + q[13] * bfhi(k1.z);
    s += q[14] * bflo(k1.w) + q[15] * bfhi(k1.w);
    s = s * 0.25f + __uint_as_float((rec & 0x7fffu) << 16) * weh;
    if (idx >= deg) s = -INFINITY;

    float p;
    if (s > m + 8.f) {               // first real edge always takes this path
      float c = __expf(m - s);       // exp(-inf)=0 on first edge
      de *= c;
#pragma unroll
      for (int d = 0; d < 16; d++) acc[d] *= c;
      m = s;
      p = 1.f;
    } else {
      p = __expf(s - m);             // bounded by e^8; NaN only on pad-only lanes
    }
    de += p;
    acc[0]  += p * bflo(v0.x); acc[1]  += p * bfhi(v0.x);
    acc[2]  += p * bflo(v0.y); acc[3]  += p * bfhi(v0.y);
    acc[4]  += p * bflo(v0.z); acc[5]  += p * bfhi(v0.z);
    acc[6]  += p * bflo(v0.w); acc[7]  += p * bfhi(v0.w);
    acc[8]  += p * bflo(v1.x); acc[9]  += p * bfhi(v1.x);
    acc[10] += p * bflo(v1.y); acc[11] += p * bfhi(v1.y);
    acc[12] += p * bflo(v1.z); acc[13] += p * bfhi(v1.z);
    acc[14] += p * bflo(v1.w); acc[15] += p * bfhi(v1.w);
  }

  // pad-only lanes (u >= deg): m stayed -inf, de/acc are NaN -> zero them
  bool live = (m > -INFINITY);
  if (!live) {
    de = 0.f;
#pragma unroll
    for (int d = 0; d < 16; d++) acc[d] = 0.f;
  }
  // merge 8 slot-chains per head: lanes {h, h+8, ..., h+56}
  float M = m;
  M = fmaxf(M, __shfl_xor(M, 8));
  M = fmaxf(M, __shfl_xor(M, 16));
  M = fmaxf(M, __shfl_xor(M, 32));
  float c = live ? __expf(m - M) : 0.f;
  de *= c;
#pragma unroll
  for (int d = 0; d < 16; d++) acc[d] *= c;
  de += __shfl_xor(de, 8); de += __shfl_xor(de, 16); de += __shfl_xor(de, 32);
#pragma unroll
  for (int d = 0; d < 16; d++) {
    acc[d] += __shfl_xor(acc[d], 8);
    acc[d] += __shfl_xor(acc[d], 16);
    acc[d] += __shfl_xor(acc[d], 32);
  }

  if (u == 0) {
    float inv = (de > 0.f) ? 1.0f / de : 0.f;
    unsigned o[8];
#pragma unroll
    for (int j = 0; j < 8; j++) {
      ushort lo = f2bf(acc[2 * j] * inv);
      ushort hi = f2bf(acc[2 * j + 1] * inv);
      o[j] = (unsigned)lo | ((unsigned)hi << 16);
    }
    *(uint4*)(op + 0) = make_uint4(o[0], o[1], o[2], o[3]);
    *(uint4*)(op + 8) = make_uint4(o[4], o[5], o[6], o[7]);
  }
}

// Wo GEMM (bf16 MFMA, batched B-loads) + residual + LayerNorm fused.
__global__ __launch_bounds__(256) void wo_ln_kernel(
    const ushort* __restrict__ AGGb, const ushort* __restrict__ Wob,
    const float* __restrict__ x, const float* __restrict__ gamma,
    const float* __restrict__ beta, float* __restrict__ out, int N) {
  int w = threadIdx.x >> 6, l = threadIdx.x & 63;
  int n0 = blockIdx.x * 64 + w * 16;
  int lr = l & 15, lg = l >> 4;
  short8 a[4];
  const ushort* arow = AGGb + (size_t)(n0 + lr) * 128 + 8 * lg;
#pragma unroll
  for (int ks = 0; ks < 4; ks++) a[ks] = *(const short8*)(arow + 32 * ks);

  f32x4 acc[8];
#pragma unroll
  for (int ctp = 0; ctp < 4; ctp++) {
    short8 b[2][4];
#pragma unroll
    for (int ci = 0; ci < 2; ci++) {
      const ushort* wrow = Wob + (size_t)((ctp * 2 + ci) * 16 + lr) * 128 + 8 * lg;
#pragma unroll
      for (int ks = 0; ks < 4; ks++) b[ci][ks] = *(const short8*)(wrow + 32 * ks);
    }
#pragma unroll
    for (int ci = 0; ci < 2; ci++) {
      int ct = ctp * 2 + ci;
      acc[ct] = (f32x4){0.f, 0.f, 0.f, 0.f};
#pragma unroll
      for (int ks = 0; ks < 4; ks++)
        acc[ct] = __builtin_amdgcn_mfma_f32_16x16x32_bf16(a[ks], b[ci][ks], acc[ct], 0, 0, 0);
    }
  }
  float g[8], bt[8];
#pragma unroll
  for (int ct = 0; ct < 8; ct++) { g[ct] = gamma[ct * 16 + lr]; bt[ct] = beta[ct * 16 + lr]; }

#pragma unroll
  for (int r = 0; r < 4; r++) {
    int row = n0 + 4 * lg + r;
    bool ok = row < N;
    float v[8], s = 0.f, s2 = 0.f;
#pragma unroll
    for (int ct = 0; ct < 8; ct++) {
      float xv = ok ? x[(size_t)row * 128 + ct * 16 + lr] : 0.f;
      v[ct] = acc[ct][r] + xv;
      s += v[ct]; s2 += v[ct] * v[ct];
    }
#pragma unroll
    for (int d = 1; d < 16; d <<= 1) { s += __shfl_xor(s, d); s2 += __shfl_xor(s2, d); }
    float mu = s * (1.f / 128.f);
    float var = s2 * (1.f / 128.f) - mu * mu;
    float rs = rsqrtf(var + 1e-5f);
    if (ok) {
#pragma unroll
      for (int ct = 0; ct < 8; ct++)
        out[(size_t)row * 128 + ct * 16 + lr] = (v[ct] - mu) * rs * g[ct] + bt[ct];
    }
  }
}

extern "C" void kernel_launch(void* const* d_in, const int* in_sizes, int n_in,
                              void* d_out, int out_size, void* d_ws, size_t ws_size,
                              hipStream_t stream) {
  const float* x     = (const float*)d_in[0];
  const int*   ei    = (const int*)d_in[1];
  const float* ew    = (const float*)d_in[2];
  const float* Wq    = (const float*)d_in[3];
  const float* Wk    = (const float*)d_in[4];
  const float* Wv    = (const float*)d_in[5];
  const float* We    = (const float*)d_in[6];
  const float* Wo    = (const float*)d_in[7];
  const float* gamma = (const float*)d_in[8];
  const float* beta  = (const float*)d_in[9];

  int N = in_sizes[0] / 128;
  int E = in_sizes[1] / 2;
  int Npad = (N + 127) & ~127;
  int QB = Npad / 128;
  int EB4 = (E + 1023) / 1024;

  char* ws = (char*)d_ws;
  ushort* Wb   = (ushort*)ws; ws += 4 * 16384 * 2;          // [Wq,Wk,Wv,Wo] bf16
  float*  Qf   = (float*)ws;  ws += (size_t)Npad * 128 * 4;
  ushort* KVb  = (ushort*)ws; ws += (size_t)Npad * 256 * 2; // [K row | V row]
  ushort* AGGb = (ushort*)ws; ws += (size_t)Npad * 128 * 2;
  int* cnt  = (int*)ws; ws += (size_t)N * 16 * 4;           // 1 counter / 64B line
  unsigned* recs = (unsigned*)ws; ws += (size_t)N * CAP * 4;
  ushort* Wob = Wb + 3 * 16384;

  hipMemsetAsync(cnt, 0, (size_t)N * 16 * 4, stream);

  prep_kernel<<<64, 256, 0, stream>>>(Wq, Wk, Wv, Wo, Wb);

  qkv_histfill_kernel<<<EB4 + QB, 256, 0, stream>>>(x, Wb, Qf, KVb, ei, ew, cnt, recs, N, E, EB4);

  edge_attn_kernel<<<N, 64, 0, stream>>>(Qf, KVb, recs, We, cnt, AGGb, N);

  wo_ln_kernel<<<Npad / 64, 256, 0, stream>>>(AGGb, Wob, x, gamma, beta, (float*)d_out, N);
}

// Round 10
// 177.137 us; speedup vs baseline: 1.0471x; 1.0471x over previous
//
#include <hip/hip_runtime.h>
#include <hip/hip_bf16.h>
#include <math.h>

// ---------------------------------------------------------------------------
// EdgeAwareAttention: B=1, N=50000, D=128, H=8, d=16, E=800000
//  prep         : Wq,Wk,Wv,Wo f32->bf16
//  qkv_histfill : INTERLEAVED 1:8 block mix —
//                 bid%9==0 -> MFMA QKV tile (2 row-tiles/wave, batched B-loads)
//                 else     -> bucket CSR scatter (1 edge/thread, atomic rank)
//  edge_attn    : wave-per-node, bucket preloaded to regs + shfl distribution,
//                 lane=(slot,head), defer-max, slot-merge via shfl_xor
//  wo_ln        : MFMA Wo GEMM + residual + LayerNorm fused -> d_out
// Bucket capacity 64: deg~Poisson(16), P(deg>64)~1e-26; r<64 clamp = safe.
// ---------------------------------------------------------------------------

#define CAP 64

typedef __attribute__((ext_vector_type(8))) short short8;
typedef __attribute__((ext_vector_type(4))) float f32x4;

static __device__ __forceinline__ ushort f2bf(float f) {
  unsigned u = __float_as_uint(f);
  u += 0x7fff + ((u >> 16) & 1);          // RNE
  return (ushort)(u >> 16);
}
static __device__ __forceinline__ float bflo(unsigned u) {   // low bf16 -> f32
  return __uint_as_float(u << 16);
}
static __device__ __forceinline__ float bfhi(unsigned u) {   // high bf16 -> f32
  return __uint_as_float(u & 0xffff0000u);
}

// W convert (4*16384 f32 -> bf16)
__global__ __launch_bounds__(256) void prep_kernel(
    const float* __restrict__ Wq, const float* __restrict__ Wk,
    const float* __restrict__ Wv, const float* __restrict__ Wo,
    ushort* __restrict__ Wb) {
  int tid = blockIdx.x * 256 + threadIdx.x;
  if (tid < 16384) {
    int i = tid * 4;
    const float* src = (i < 16384) ? Wq : (i < 32768) ? Wk : (i < 49152) ? Wv : Wo;
    int off = i & 16383;
    float4 v = *(const float4*)(src + off);
    *(ushort4*)(Wb + i) = make_ushort4(f2bf(v.x), f2bf(v.y), f2bf(v.z), f2bf(v.w));
  }
}

// Interleaved fused kernel: bid%9==0 -> GEMM tile bid/9; else scatter.
// Scatter: recs[s*CAP + r] = dst<<15 | (bf16(ew) & 0x7fff), r = atomic rank.
// KVb layout: row n = [K[0..128) | V[0..128)] (256 ushorts).
__global__ __launch_bounds__(256) void qkv_histfill_kernel(
    const float* __restrict__ x, const ushort* __restrict__ Wb,   // Wb: [3][128][128]
    float* __restrict__ Qf, ushort* __restrict__ KVb,
    const int* __restrict__ ei, const float* __restrict__ ew,
    int* __restrict__ cnt, unsigned* __restrict__ recs,
    int N, int E, int QB) {
  int bid = (int)blockIdx.x;
  int k = bid / 9, r9 = bid - k * 9;
  if (r9 != 0 || k >= QB) {
    // scatter block: sidx = 8k + r9 - 1 (r9>0); exact cover of [0, EB)
    int sidx = 8 * k + r9 - 1;
    int e = sidx * 256 + threadIdx.x;
    if (e < E) {
      int s = ei[e];
      int r = atomicAdd(&cnt[s], 1);
      if (r < CAP) {
        unsigned pk = ((unsigned)ei[E + e] << 15) | ((unsigned)f2bf(ew[e]) & 0x7fffu);
        recs[((size_t)s << 6) + r] = pk;
      }
    }
    return;
  }
  int w = threadIdx.x >> 6, l = threadIdx.x & 63;
  int n0 = k * 128 + w * 32;
  int lr = l & 15, lg = l >> 4;

  short8 a[2][4];
#pragma unroll
  for (int rt = 0; rt < 2; rt++) {
    int arow = n0 + rt * 16 + lr;
    if (arow < N) {
      const float* xrow = x + (size_t)arow * 128 + 8 * lg;
      float4 x0[4], x1[4];
#pragma unroll
      for (int ks = 0; ks < 4; ks++) {
        x0[ks] = *(const float4*)(xrow + 32 * ks);
        x1[ks] = *(const float4*)(xrow + 32 * ks + 4);
      }
#pragma unroll
      for (int ks = 0; ks < 4; ks++) {
        short8 t;
        t[0] = f2bf(x0[ks].x); t[1] = f2bf(x0[ks].y); t[2] = f2bf(x0[ks].z); t[3] = f2bf(x0[ks].w);
        t[4] = f2bf(x1[ks].x); t[5] = f2bf(x1[ks].y); t[6] = f2bf(x1[ks].z); t[7] = f2bf(x1[ks].w);
        a[rt][ks] = t;
      }
    } else {
#pragma unroll
      for (int ks = 0; ks < 4; ks++) a[rt][ks] = (short8){0,0,0,0,0,0,0,0};
    }
  }

  bool ok[2][4];
#pragma unroll
  for (int rt = 0; rt < 2; rt++)
#pragma unroll
    for (int r = 0; r < 4; r++) ok[rt][r] = (n0 + rt * 16 + 4 * lg + r) < N;

#pragma unroll
  for (int m = 0; m < 3; m++) {
    const ushort* Wm = Wb + m * 16384;
#pragma unroll
    for (int ctp = 0; ctp < 4; ctp++) {
      short8 b[2][4];
#pragma unroll
      for (int ci = 0; ci < 2; ci++) {
        const ushort* wrow = Wm + (size_t)((ctp * 2 + ci) * 16 + lr) * 128 + 8 * lg;
#pragma unroll
        for (int ks = 0; ks < 4; ks++) b[ci][ks] = *(const short8*)(wrow + 32 * ks);
      }
      f32x4 acc[2][2];
#pragma unroll
      for (int rt = 0; rt < 2; rt++)
#pragma unroll
        for (int ci = 0; ci < 2; ci++) {
          acc[rt][ci] = (f32x4){0.f, 0.f, 0.f, 0.f};
#pragma unroll
          for (int ks = 0; ks < 4; ks++)
            acc[rt][ci] = __builtin_amdgcn_mfma_f32_16x16x32_bf16(a[rt][ks], b[ci][ks], acc[rt][ci], 0, 0, 0);
        }
#pragma unroll
      for (int rt = 0; rt < 2; rt++)
#pragma unroll
        for (int ci = 0; ci < 2; ci++) {
          int c = (ctp * 2 + ci) * 16 + lr;
#pragma unroll
          for (int r = 0; r < 4; r++) {
            if (ok[rt][r]) {
              size_t row = (size_t)(n0 + rt * 16 + 4 * lg + r);
              if (m == 0)      Qf[row * 128 + c] = acc[rt][ci][r];
              else if (m == 1) KVb[row * 256 + c] = f2bf(acc[rt][ci][r]);
              else             KVb[row * 256 + 128 + c] = f2bf(acc[rt][ci][r]);
            }
          }
        }
    }
  }
}

// Wave-per-node: 64-thread block, lane = (slot u = l>>3, head h = l&7).
// Bucket preloaded: lane l holds rb[min(l,deg-1)]; per-iter rec via shfl.
// Per-lane online softmax chain (defer-max THR=8); slot-merge via shfl_xor.
__global__ __launch_bounds__(64) void edge_attn_kernel(
    const float* __restrict__ Qf, const ushort* __restrict__ KVb,
    const unsigned* __restrict__ recs, const float* __restrict__ We,
    const int* __restrict__ cnt, ushort* __restrict__ AGGb, int N) {
  int n = blockIdx.x;
  int l = threadIdx.x;
  int u = l >> 3, h = l & 7;
  int deg = min(cnt[n], CAP);
  ushort* op = AGGb + (size_t)n * 128 + (h << 4);

  if (deg <= 0) {                    // no edges: agg = 0
    if (u == 0) {
      *(uint4*)(op + 0) = make_uint4(0, 0, 0, 0);
      *(uint4*)(op + 8) = make_uint4(0, 0, 0, 0);
    }
    return;
  }

  const unsigned* rb = recs + ((size_t)n << 6);
  unsigned myrec = rb[min(l, deg - 1)];          // coalesced bucket preload

  float q[16];
  const float* qp = Qf + (size_t)n * 128 + (h << 4);
  *(float4*)(q + 0)  = *(const float4*)(qp + 0);
  *(float4*)(q + 4)  = *(const float4*)(qp + 4);
  *(float4*)(q + 8)  = *(const float4*)(qp + 8);
  *(float4*)(q + 12) = *(const float4*)(qp + 12);
  float weh = We[h];

  float m = -INFINITY, de = 0.f;
  float acc[16];
#pragma unroll
  for (int d = 0; d < 16; d++) acc[d] = 0.f;

  for (int base = 0; base < deg; base += 8) {
    int idx = base + u;                          // <= 63
    unsigned rec = __shfl(myrec, idx);           // lanes >= deg hold rb[deg-1]
    const ushort* kv = KVb + (((rec >> 15) << 8) + (h << 4));
    uint4 k0 = *(const uint4*)kv;
    uint4 k1 = *(const uint4*)(kv + 8);
    uint4 v0 = *(const uint4*)(kv + 128);
    uint4 v1 = *(const uint4*)(kv + 136);

    float s;
    s  = q[0]  * bflo(k0.x) + q[1]  * bfhi(k0.x);
    s += q[2]  * bflo(k0.y) + q[3]  * bfhi(k0.y);
    s += q[4]  * bflo(k0.z) + q[5]  * bfhi(k0.z);
    s += q[6]  * bflo(k0.w) + q[7]  * bfhi(k0.w);
    s += q[8]  * bflo(k1.x) + q[9]  * bfhi(k1.x);
    s += q[10] * bflo(k1.y) + q[11] * bfhi(k1.y);
    s += q[12] * bflo(k1.z) + q[13] * bfhi(k1.z);
    s += q[14] * bflo(k1.w) + q[15] * bfhi(k1.w);
    s = s * 0.25f + __uint_as_float((rec & 0x7fffu) << 16) * weh;
    if (idx >= deg) s = -INFINITY;

    float p;
    if (s > m + 8.f) {               // first real edge always takes this path
      float c = __expf(m - s);       // exp(-inf)=0 on first edge
      de *= c;
#pragma unroll
      for (int d = 0; d < 16; d++) acc[d] *= c;
      m = s;
      p = 1.f;
    } else {
      p = __expf(s - m);             // bounded by e^8; NaN only on pad-only lanes
    }
    de += p;
    acc[0]  += p * bflo(v0.x); acc[1]  += p * bfhi(v0.x);
    acc[2]  += p * bflo(v0.y); acc[3]  += p * bfhi(v0.y);
    acc[4]  += p * bflo(v0.z); acc[5]  += p * bfhi(v0.z);
    acc[6]  += p * bflo(v0.w); acc[7]  += p * bfhi(v0.w);
    acc[8]  += p * bflo(v1.x); acc[9]  += p * bfhi(v1.x);
    acc[10] += p * bflo(v1.y); acc[11] += p * bfhi(v1.y);
    acc[12] += p * bflo(v1.z); acc[13] += p * bfhi(v1.z);
    acc[14] += p * bflo(v1.w); acc[15] += p * bfhi(v1.w);
  }

  // pad-only lanes (u >= deg): m stayed -inf, de/acc are NaN -> zero them
  bool live = (m > -INFINITY);
  if (!live) {
    de = 0.f;
#pragma unroll
    for (int d = 0; d < 16; d++) acc[d] = 0.f;
  }
  // merge 8 slot-chains per head: lanes {h, h+8, ..., h+56}
  float M = m;
  M = fmaxf(M, __shfl_xor(M, 8));
  M = fmaxf(M, __shfl_xor(M, 16));
  M = fmaxf(M, __shfl_xor(M, 32));
  float c = live ? __expf(m - M) : 0.f;
  de *= c;
#pragma unroll
  for (int d = 0; d < 16; d++) acc[d] *= c;
  de += __shfl_xor(de, 8); de += __shfl_xor(de, 16); de += __shfl_xor(de, 32);
#pragma unroll
  for (int d = 0; d < 16; d++) {
    acc[d] += __shfl_xor(acc[d], 8);
    acc[d] += __shfl_xor(acc[d], 16);
    acc[d] += __shfl_xor(acc[d], 32);
  }

  if (u == 0) {
    float inv = (de > 0.f) ? 1.0f / de : 0.f;
    unsigned o[8];
#pragma unroll
    for (int j = 0; j < 8; j++) {
      ushort lo = f2bf(acc[2 * j] * inv);
      ushort hi = f2bf(acc[2 * j + 1] * inv);
      o[j] = (unsigned)lo | ((unsigned)hi << 16);
    }
    *(uint4*)(op + 0) = make_uint4(o[0], o[1], o[2], o[3]);
    *(uint4*)(op + 8) = make_uint4(o[4], o[5], o[6], o[7]);
  }
}

// Wo GEMM (bf16 MFMA, batched B-loads) + residual + LayerNorm fused.
__global__ __launch_bounds__(256) void wo_ln_kernel(
    const ushort* __restrict__ AGGb, const ushort* __restrict__ Wob,
    const float* __restrict__ x, const float* __restrict__ gamma,
    const float* __restrict__ beta, float* __restrict__ out, int N) {
  int w = threadIdx.x >> 6, l = threadIdx.x & 63;
  int n0 = blockIdx.x * 64 + w * 16;
  int lr = l & 15, lg = l >> 4;
  short8 a[4];
  const ushort* arow = AGGb + (size_t)(n0 + lr) * 128 + 8 * lg;
#pragma unroll
  for (int ks = 0; ks < 4; ks++) a[ks] = *(const short8*)(arow + 32 * ks);

  f32x4 acc[8];
#pragma unroll
  for (int ctp = 0; ctp < 4; ctp++) {
    short8 b[2][4];
#pragma unroll
    for (int ci = 0; ci < 2; ci++) {
      const ushort* wrow = Wob + (size_t)((ctp * 2 + ci) * 16 + lr) * 128 + 8 * lg;
#pragma unroll
      for (int ks = 0; ks < 4; ks++) b[ci][ks] = *(const short8*)(wrow + 32 * ks);
    }
#pragma unroll
    for (int ci = 0; ci < 2; ci++) {
      int ct = ctp * 2 + ci;
      acc[ct] = (f32x4){0.f, 0.f, 0.f, 0.f};
#pragma unroll
      for (int ks = 0; ks < 4; ks++)
        acc[ct] = __builtin_amdgcn_mfma_f32_16x16x32_bf16(a[ks], b[ci][ks], acc[ct], 0, 0, 0);
    }
  }
  float g[8], bt[8];
#pragma unroll
  for (int ct = 0; ct < 8; ct++) { g[ct] = gamma[ct * 16 + lr]; bt[ct] = beta[ct * 16 + lr]; }

#pragma unroll
  for (int r = 0; r < 4; r++) {
    int row = n0 + 4 * lg + r;
    bool ok = row < N;
    float v[8], s = 0.f, s2 = 0.f;
#pragma unroll
    for (int ct = 0; ct < 8; ct++) {
      float xv = ok ? x[(size_t)row * 128 + ct * 16 + lr] : 0.f;
      v[ct] = acc[ct][r] + xv;
      s += v[ct]; s2 += v[ct] * v[ct];
    }
#pragma unroll
    for (int d = 1; d < 16; d <<= 1) { s += __shfl_xor(s, d); s2 += __shfl_xor(s2, d); }
    float mu = s * (1.f / 128.f);
    float var = s2 * (1.f / 128.f) - mu * mu;
    float rs = rsqrtf(var + 1e-5f);
    if (ok) {
#pragma unroll
      for (int ct = 0; ct < 8; ct++)
        out[(size_t)row * 128 + ct * 16 + lr] = (v[ct] - mu) * rs * g[ct] + bt[ct];
    }
  }
}

extern "C" void kernel_launch(void* const* d_in, const int* in_sizes, int n_in,
                              void* d_out, int out_size, void* d_ws, size_t ws_size,
                              hipStream_t stream) {
  const float* x     = (const float*)d_in[0];
  const int*   ei    = (const int*)d_in[1];
  const float* ew    = (const float*)d_in[2];
  const float* Wq    = (const float*)d_in[3];
  const float* Wk    = (const float*)d_in[4];
  const float* Wv    = (const float*)d_in[5];
  const float* We    = (const float*)d_in[6];
  const float* Wo    = (const float*)d_in[7];
  const float* gamma = (const float*)d_in[8];
  const float* beta  = (const float*)d_in[9];

  int N = in_sizes[0] / 128;
  int E = in_sizes[1] / 2;
  int Npad = (N + 127) & ~127;
  int QB = Npad / 128;                   // 391 GEMM blocks
  int EB = (E + 255) / 256;              // 3125 scatter blocks
  int T  = QB + EB;                      // interleaved grid (9*QB >= T required)

  char* ws = (char*)d_ws;
  ushort* Wb   = (ushort*)ws; ws += 4 * 16384 * 2;          // [Wq,Wk,Wv,Wo] bf16
  float*  Qf   = (float*)ws;  ws += (size_t)Npad * 128 * 4;
  ushort* KVb  = (ushort*)ws; ws += (size_t)Npad * 256 * 2; // [K row | V row]
  ushort* AGGb = (ushort*)ws; ws += (size_t)Npad * 128 * 2;
  int* cnt  = (int*)ws; ws += (size_t)N * 4;
  unsigned* recs = (unsigned*)ws; ws += (size_t)N * CAP * 4;
  ushort* Wob = Wb + 3 * 16384;

  hipMemsetAsync(cnt, 0, (size_t)N * 4, stream);

  prep_kernel<<<64, 256, 0, stream>>>(Wq, Wk, Wv, Wo, Wb);

  qkv_histfill_kernel<<<T, 256, 0, stream>>>(x, Wb, Qf, KVb, ei, ew, cnt, recs, N, E, QB);

  edge_attn_kernel<<<N, 64, 0, stream>>>(Qf, KVb, recs, We, cnt, AGGb, N);

  wo_ln_kernel<<<Npad / 64, 256, 0, stream>>>(AGGb, Wob, x, gamma, beta, (float*)d_out, N);
}

// Round 11
// 168.881 us; speedup vs baseline: 1.0983x; 1.0489x over previous
//
#include <hip/hip_runtime.h>
#include <hip/hip_bf16.h>
#include <math.h>

// ---------------------------------------------------------------------------
// EdgeAwareAttention: B=1, N=50000, D=128, H=8, d=16, E=800000
//  prep         : Wq,Wk,Wv,Wo f32->bf16
//  qkv_histfill : [blocks 0..QB)  MFMA QKV (2 row-tiles/wave, batched B-loads)
//                 [blocks QB..)   bucket CSR scatter, 1 edge/thread,
//                                 NON-TEMPORAL record store (no write-allocate)
//  edge_attn    : 4 waves/block, wave-per-node, bucket preload + shfl,
//                 lane=(slot,head), defer-max, slot-merge via shfl_xor
//  wo_ln        : MFMA Wo GEMM + residual + LayerNorm fused -> d_out
// Bucket capacity 64: deg~Poisson(16), P(deg>64)~1e-26; r<64 clamp = safe.
// ---------------------------------------------------------------------------

#define CAP 64

typedef __attribute__((ext_vector_type(8))) short short8;
typedef __attribute__((ext_vector_type(4))) float f32x4;

static __device__ __forceinline__ ushort f2bf(float f) {
  unsigned u = __float_as_uint(f);
  u += 0x7fff + ((u >> 16) & 1);          // RNE
  return (ushort)(u >> 16);
}
static __device__ __forceinline__ float bflo(unsigned u) {   // low bf16 -> f32
  return __uint_as_float(u << 16);
}
static __device__ __forceinline__ float bfhi(unsigned u) {   // high bf16 -> f32
  return __uint_as_float(u & 0xffff0000u);
}

// W convert (4*16384 f32 -> bf16)
__global__ __launch_bounds__(256) void prep_kernel(
    const float* __restrict__ Wq, const float* __restrict__ Wk,
    const float* __restrict__ Wv, const float* __restrict__ Wo,
    ushort* __restrict__ Wb) {
  int tid = blockIdx.x * 256 + threadIdx.x;
  if (tid < 16384) {
    int i = tid * 4;
    const float* src = (i < 16384) ? Wq : (i < 32768) ? Wk : (i < 49152) ? Wv : Wo;
    int off = i & 16383;
    float4 v = *(const float4*)(src + off);
    *(ushort4*)(Wb + i) = make_ushort4(f2bf(v.x), f2bf(v.y), f2bf(v.z), f2bf(v.w));
  }
}

// Fused: QKV MFMA GEMM (blocks < QB) | bucket CSR scatter (blocks >= QB).
// Scatter: recs[s*CAP + r] = dst<<15 | (bf16(ew) & 0x7fff), r = atomic rank.
// Record store is non-temporal: scattered 4B stores would otherwise
// write-allocate (RFO) a 64B line each -> L2 miss-queue bound.
// KVb layout: row n = [K[0..128) | V[0..128)] (256 ushorts).
__global__ __launch_bounds__(256) void qkv_histfill_kernel(
    const float* __restrict__ x, const ushort* __restrict__ Wb,   // Wb: [3][128][128]
    float* __restrict__ Qf, ushort* __restrict__ KVb,
    const int* __restrict__ ei, const float* __restrict__ ew,
    int* __restrict__ cnt, unsigned* __restrict__ recs,
    int N, int E, int QB) {
  if ((int)blockIdx.x >= QB) {
    int e = ((int)blockIdx.x - QB) * 256 + threadIdx.x;
    if (e < E) {
      int s = ei[e];
      int r = atomicAdd(&cnt[s], 1);
      if (r < CAP) {
        unsigned pk = ((unsigned)ei[E + e] << 15) | ((unsigned)f2bf(ew[e]) & 0x7fffu);
        __builtin_nontemporal_store(pk, &recs[((size_t)s << 6) + r]);
      }
    }
    return;
  }
  int w = threadIdx.x >> 6, l = threadIdx.x & 63;
  int n0 = (int)blockIdx.x * 128 + w * 32;
  int lr = l & 15, lg = l >> 4;

  short8 a[2][4];
#pragma unroll
  for (int rt = 0; rt < 2; rt++) {
    int arow = n0 + rt * 16 + lr;
    if (arow < N) {
      const float* xrow = x + (size_t)arow * 128 + 8 * lg;
      float4 x0[4], x1[4];
#pragma unroll
      for (int ks = 0; ks < 4; ks++) {
        x0[ks] = *(const float4*)(xrow + 32 * ks);
        x1[ks] = *(const float4*)(xrow + 32 * ks + 4);
      }
#pragma unroll
      for (int ks = 0; ks < 4; ks++) {
        short8 t;
        t[0] = f2bf(x0[ks].x); t[1] = f2bf(x0[ks].y); t[2] = f2bf(x0[ks].z); t[3] = f2bf(x0[ks].w);
        t[4] = f2bf(x1[ks].x); t[5] = f2bf(x1[ks].y); t[6] = f2bf(x1[ks].z); t[7] = f2bf(x1[ks].w);
        a[rt][ks] = t;
      }
    } else {
#pragma unroll
      for (int ks = 0; ks < 4; ks++) a[rt][ks] = (short8){0,0,0,0,0,0,0,0};
    }
  }

  bool ok[2][4];
#pragma unroll
  for (int rt = 0; rt < 2; rt++)
#pragma unroll
    for (int r = 0; r < 4; r++) ok[rt][r] = (n0 + rt * 16 + 4 * lg + r) < N;

#pragma unroll
  for (int m = 0; m < 3; m++) {
    const ushort* Wm = Wb + m * 16384;
#pragma unroll
    for (int ctp = 0; ctp < 4; ctp++) {
      short8 b[2][4];
#pragma unroll
      for (int ci = 0; ci < 2; ci++) {
        const ushort* wrow = Wm + (size_t)((ctp * 2 + ci) * 16 + lr) * 128 + 8 * lg;
#pragma unroll
        for (int ks = 0; ks < 4; ks++) b[ci][ks] = *(const short8*)(wrow + 32 * ks);
      }
      f32x4 acc[2][2];
#pragma unroll
      for (int rt = 0; rt < 2; rt++)
#pragma unroll
        for (int ci = 0; ci < 2; ci++) {
          acc[rt][ci] = (f32x4){0.f, 0.f, 0.f, 0.f};
#pragma unroll
          for (int ks = 0; ks < 4; ks++)
            acc[rt][ci] = __builtin_amdgcn_mfma_f32_16x16x32_bf16(a[rt][ks], b[ci][ks], acc[rt][ci], 0, 0, 0);
        }
#pragma unroll
      for (int rt = 0; rt < 2; rt++)
#pragma unroll
        for (int ci = 0; ci < 2; ci++) {
          int c = (ctp * 2 + ci) * 16 + lr;
#pragma unroll
          for (int r = 0; r < 4; r++) {
            if (ok[rt][r]) {
              size_t row = (size_t)(n0 + rt * 16 + 4 * lg + r);
              if (m == 0)      Qf[row * 128 + c] = acc[rt][ci][r];
              else if (m == 1) KVb[row * 256 + c] = f2bf(acc[rt][ci][r]);
              else             KVb[row * 256 + 128 + c] = f2bf(acc[rt][ci][r]);
            }
          }
        }
    }
  }
}

// 4 waves/block, wave-per-node. Lane = (slot u = l>>3, head h = l&7).
// Bucket preloaded: lane l holds rb[min(l,deg-1)]; per-iter rec via shfl.
// Per-lane online softmax chain (defer-max THR=8); slot-merge via shfl_xor.
__global__ __launch_bounds__(256) void edge_attn_kernel(
    const float* __restrict__ Qf, const ushort* __restrict__ KVb,
    const unsigned* __restrict__ recs, const float* __restrict__ We,
    const int* __restrict__ cnt, ushort* __restrict__ AGGb, int N) {
  int wv = threadIdx.x >> 6, l = threadIdx.x & 63;
  int n = blockIdx.x * 4 + wv;
  if (n >= N) return;
  int u = l >> 3, h = l & 7;
  int deg = min(cnt[n], CAP);
  ushort* op = AGGb + (size_t)n * 128 + (h << 4);

  if (deg <= 0) {                    // no edges: agg = 0
    if (u == 0) {
      *(uint4*)(op + 0) = make_uint4(0, 0, 0, 0);
      *(uint4*)(op + 8) = make_uint4(0, 0, 0, 0);
    }
    return;
  }

  const unsigned* rb = recs + ((size_t)n << 6);
  unsigned myrec = rb[min(l, deg - 1)];          // coalesced bucket preload

  float q[16];
  const float* qp = Qf + (size_t)n * 128 + (h << 4);
  *(float4*)(q + 0)  = *(const float4*)(qp + 0);
  *(float4*)(q + 4)  = *(const float4*)(qp + 4);
  *(float4*)(q + 8)  = *(const float4*)(qp + 8);
  *(float4*)(q + 12) = *(const float4*)(qp + 12);
  float weh = We[h];

  float m = -INFINITY, de = 0.f;
  float acc[16];
#pragma unroll
  for (int d = 0; d < 16; d++) acc[d] = 0.f;

  for (int base = 0; base < deg; base += 8) {
    int idx = base + u;                          // <= 63
    unsigned rec = __shfl(myrec, idx);           // lanes >= deg hold rb[deg-1]
    const ushort* kv = KVb + (((rec >> 15) << 8) + (h << 4));
    uint4 k0 = *(const uint4*)kv;
    uint4 k1 = *(const uint4*)(kv + 8);
    uint4 v0 = *(const uint4*)(kv + 128);
    uint4 v1 = *(const uint4*)(kv + 136);

    float s;
    s  = q[0]  * bflo(k0.x) + q[1]  * bfhi(k0.x);
    s += q[2]  * bflo(k0.y) + q[3]  * bfhi(k0.y);
    s += q[4]  * bflo(k0.z) + q[5]  * bfhi(k0.z);
    s += q[6]  * bflo(k0.w) + q[7]  * bfhi(k0.w);
    s += q[8]  * bflo(k1.x) + q[9]  * bfhi(k1.x);
    s += q[10] * bflo(k1.y) + q[11] * bfhi(k1.y);
    s += q[12] * bflo(k1.z) + q[13] * bfhi(k1.z);
    s += q[14] * bflo(k1.w) + q[15] * bfhi(k1.w);
    s = s * 0.25f + __uint_as_float((rec & 0x7fffu) << 16) * weh;
    if (idx >= deg) s = -INFINITY;

    float p;
    if (s > m + 8.f) {               // first real edge always takes this path
      float c = __expf(m - s);       // exp(-inf)=0 on first edge
      de *= c;
#pragma unroll
      for (int d = 0; d < 16; d++) acc[d] *= c;
      m = s;
      p = 1.f;
    } else {
      p = __expf(s - m);             // bounded by e^8; NaN only on pad-only lanes
    }
    de += p;
    acc[0]  += p * bflo(v0.x); acc[1]  += p * bfhi(v0.x);
    acc[2]  += p * bflo(v0.y); acc[3]  += p * bfhi(v0.y);
    acc[4]  += p * bflo(v0.z); acc[5]  += p * bfhi(v0.z);
    acc[6]  += p * bflo(v0.w); acc[7]  += p * bfhi(v0.w);
    acc[8]  += p * bflo(v1.x); acc[9]  += p * bfhi(v1.x);
    acc[10] += p * bflo(v1.y); acc[11] += p * bfhi(v1.y);
    acc[12] += p * bflo(v1.z); acc[13] += p * bfhi(v1.z);
    acc[14] += p * bflo(v1.w); acc[15] += p * bfhi(v1.w);
  }

  // pad-only lanes (u >= deg): m stayed -inf, de/acc are NaN -> zero them
  bool live = (m > -INFINITY);
  if (!live) {
    de = 0.f;
#pragma unroll
    for (int d = 0; d < 16; d++) acc[d] = 0.f;
  }
  // merge 8 slot-chains per head: lanes {h, h+8, ..., h+56}
  float M = m;
  M = fmaxf(M, __shfl_xor(M, 8));
  M = fmaxf(M, __shfl_xor(M, 16));
  M = fmaxf(M, __shfl_xor(M, 32));
  float c = live ? __expf(m - M) : 0.f;
  de *= c;
#pragma unroll
  for (int d = 0; d < 16; d++) acc[d] *= c;
  de += __shfl_xor(de, 8); de += __shfl_xor(de, 16); de += __shfl_xor(de, 32);
#pragma unroll
  for (int d = 0; d < 16; d++) {
    acc[d] += __shfl_xor(acc[d], 8);
    acc[d] += __shfl_xor(acc[d], 16);
    acc[d] += __shfl_xor(acc[d], 32);
  }

  if (u == 0) {
    float inv = (de > 0.f) ? 1.0f / de : 0.f;
    unsigned o[8];
#pragma unroll
    for (int j = 0; j < 8; j++) {
      ushort lo = f2bf(acc[2 * j] * inv);
      ushort hi = f2bf(acc[2 * j + 1] * inv);
      o[j] = (unsigned)lo | ((unsigned)hi << 16);
    }
    *(uint4*)(op + 0) = make_uint4(o[0], o[1], o[2], o[3]);
    *(uint4*)(op + 8) = make_uint4(o[4], o[5], o[6], o[7]);
  }
}

// Wo GEMM (bf16 MFMA, batched B-loads) + residual + LayerNorm fused.
__global__ __launch_bounds__(256) void wo_ln_kernel(
    const ushort* __restrict__ AGGb, const ushort* __restrict__ Wob,
    const float* __restrict__ x, const float* __restrict__ gamma,
    const float* __restrict__ beta, float* __restrict__ out, int N) {
  int w = threadIdx.x >> 6, l = threadIdx.x & 63;
  int n0 = blockIdx.x * 64 + w * 16;
  int lr = l & 15, lg = l >> 4;
  short8 a[4];
  const ushort* arow = AGGb + (size_t)(n0 + lr) * 128 + 8 * lg;
#pragma unroll
  for (int ks = 0; ks < 4; ks++) a[ks] = *(const short8*)(arow + 32 * ks);

  f32x4 acc[8];
#pragma unroll
  for (int ctp = 0; ctp < 4; ctp++) {
    short8 b[2][4];
#pragma unroll
    for (int ci = 0; ci < 2; ci++) {
      const ushort* wrow = Wob + (size_t)((ctp * 2 + ci) * 16 + lr) * 128 + 8 * lg;
#pragma unroll
      for (int ks = 0; ks < 4; ks++) b[ci][ks] = *(const short8*)(wrow + 32 * ks);
    }
#pragma unroll
    for (int ci = 0; ci < 2; ci++) {
      int ct = ctp * 2 + ci;
      acc[ct] = (f32x4){0.f, 0.f, 0.f, 0.f};
#pragma unroll
      for (int ks = 0; ks < 4; ks++)
        acc[ct] = __builtin_amdgcn_mfma_f32_16x16x32_bf16(a[ks], b[ci][ks], acc[ct], 0, 0, 0);
    }
  }
  float g[8], bt[8];
#pragma unroll
  for (int ct = 0; ct < 8; ct++) { g[ct] = gamma[ct * 16 + lr]; bt[ct] = beta[ct * 16 + lr]; }

#pragma unroll
  for (int r = 0; r < 4; r++) {
    int row = n0 + 4 * lg + r;
    bool ok = row < N;
    float v[8], s = 0.f, s2 = 0.f;
#pragma unroll
    for (int ct = 0; ct < 8; ct++) {
      float xv = ok ? x[(size_t)row * 128 + ct * 16 + lr] : 0.f;
      v[ct] = acc[ct][r] + xv;
      s += v[ct]; s2 += v[ct] * v[ct];
    }
#pragma unroll
    for (int d = 1; d < 16; d <<= 1) { s += __shfl_xor(s, d); s2 += __shfl_xor(s2, d); }
    float mu = s * (1.f / 128.f);
    float var = s2 * (1.f / 128.f) - mu * mu;
    float rs = rsqrtf(var + 1e-5f);
    if (ok) {
#pragma unroll
      for (int ct = 0; ct < 8; ct++)
        out[(size_t)row * 128 + ct * 16 + lr] = (v[ct] - mu) * rs * g[ct] + bt[ct];
    }
  }
}

extern "C" void kernel_launch(void* const* d_in, const int* in_sizes, int n_in,
                              void* d_out, int out_size, void* d_ws, size_t ws_size,
                              hipStream_t stream) {
  const float* x     = (const float*)d_in[0];
  const int*   ei    = (const int*)d_in[1];
  const float* ew    = (const float*)d_in[2];
  const float* Wq    = (const float*)d_in[3];
  const float* Wk    = (const float*)d_in[4];
  const float* Wv    = (const float*)d_in[5];
  const float* We    = (const float*)d_in[6];
  const float* Wo    = (const float*)d_in[7];
  const float* gamma = (const float*)d_in[8];
  const float* beta  = (const float*)d_in[9];

  int N = in_sizes[0] / 128;
  int E = in_sizes[1] / 2;
  int Npad = (N + 127) & ~127;
  int QB = Npad / 128;
  int EB = (E + 255) / 256;

  char* ws = (char*)d_ws;
  ushort* Wb   = (ushort*)ws; ws += 4 * 16384 * 2;          // [Wq,Wk,Wv,Wo] bf16
  float*  Qf   = (float*)ws;  ws += (size_t)Npad * 128 * 4;
  ushort* KVb  = (ushort*)ws; ws += (size_t)Npad * 256 * 2; // [K row | V row]
  ushort* AGGb = (ushort*)ws; ws += (size_t)Npad * 128 * 2;
  int* cnt  = (int*)ws; ws += (size_t)N * 4;
  unsigned* recs = (unsigned*)ws; ws += (size_t)N * CAP * 4;
  ushort* Wob = Wb + 3 * 16384;

  hipMemsetAsync(cnt, 0, (size_t)N * 4, stream);

  prep_kernel<<<64, 256, 0, stream>>>(Wq, Wk, Wv, Wo, Wb);

  qkv_histfill_kernel<<<QB + EB, 256, 0, stream>>>(x, Wb, Qf, KVb, ei, ew, cnt, recs, N, E, QB);

  edge_attn_kernel<<<(N + 3) / 4, 256, 0, stream>>>(Qf, KVb, recs, We, cnt, AGGb, N);

  wo_ln_kernel<<<Npad / 64, 256, 0, stream>>>(AGGb, Wob, x, gamma, beta, (float*)d_out, N);
}

// Round 12
// 163.744 us; speedup vs baseline: 1.1327x; 1.0314x over previous
//
#include <hip/hip_runtime.h>
#include <hip/hip_bf16.h>
#include <math.h>

// ---------------------------------------------------------------------------
// EdgeAwareAttention: B=1, N=50000, D=128, H=8, d=16, E=800000
//  prep         : Wq,Wk,Wv,Wo f32->bf16
//  qkv_histfill : [blocks 0..QB)  MFMA QKV (1 row-tile/wave, 64 rows/block)
//                 [blocks QB..)   XCD-partitioned bucket scatter: group=bid%8
//                                 handles src range [N*p/8, N*(p+1)/8) so each
//                                 node's bucket lines are written by ONE XCD
//                                 (L2-resident accumulation, single writeback)
//  edge_attn    : 4 waves/block, wave-per-node, bucket preload + shfl,
//                 lane=(slot,head), defer-max, slot-merge via shfl_xor
//  wo_ln        : MFMA Wo GEMM + residual + LayerNorm fused -> d_out
// Bucket capacity 64: deg~Poisson(16), P(deg>64)~1e-26; r<64 clamp = safe.
// ---------------------------------------------------------------------------

#define CAP 64

typedef __attribute__((ext_vector_type(8))) short short8;
typedef __attribute__((ext_vector_type(4))) float f32x4;

static __device__ __forceinline__ ushort f2bf(float f) {
  unsigned u = __float_as_uint(f);
  u += 0x7fff + ((u >> 16) & 1);          // RNE
  return (ushort)(u >> 16);
}
static __device__ __forceinline__ float bflo(unsigned u) {   // low bf16 -> f32
  return __uint_as_float(u << 16);
}
static __device__ __forceinline__ float bfhi(unsigned u) {   // high bf16 -> f32
  return __uint_as_float(u & 0xffff0000u);
}

// W convert (4*16384 f32 -> bf16)
__global__ __launch_bounds__(256) void prep_kernel(
    const float* __restrict__ Wq, const float* __restrict__ Wk,
    const float* __restrict__ Wv, const float* __restrict__ Wo,
    ushort* __restrict__ Wb) {
  int tid = blockIdx.x * 256 + threadIdx.x;
  if (tid < 16384) {
    int i = tid * 4;
    const float* src = (i < 16384) ? Wq : (i < 32768) ? Wk : (i < 49152) ? Wv : Wo;
    int off = i & 16383;
    float4 v = *(const float4*)(src + off);
    *(ushort4*)(Wb + i) = make_ushort4(f2bf(v.x), f2bf(v.y), f2bf(v.z), f2bf(v.w));
  }
}

// Fused: QKV MFMA GEMM (blocks < QB) | XCD-partitioned scatter (blocks >= QB).
// Scatter: group p=(bid-QB)%8 (maps to XCD p under round-robin dispatch);
// block k=(bid-QB)/8 scans edge chunk [k*2048,(k+1)*2048), 8 edges/thread,
// filters src in group range, then atomic-rank + bucket store (plain, cached).
// KVb layout: row n = [K[0..128) | V[0..128)] (256 ushorts).
__global__ __launch_bounds__(256) void qkv_histfill_kernel(
    const float* __restrict__ x, const ushort* __restrict__ Wb,   // Wb: [3][128][128]
    float* __restrict__ Qf, ushort* __restrict__ KVb,
    const int* __restrict__ ei, const float* __restrict__ ew,
    int* __restrict__ cnt, unsigned* __restrict__ recs,
    int N, int E, int QB) {
  if ((int)blockIdx.x >= QB) {
    int sb = (int)blockIdx.x - QB;
    int p  = sb & 7;                     // XCD group (round-robin heuristic)
    int k  = sb >> 3;
    int lo = (int)((long)N * p >> 3);
    int hi = (int)((long)N * (p + 1) >> 3);
    int e0 = k * 2048 + (int)threadIdx.x * 8;
#pragma unroll
    for (int i = 0; i < 8; i++) {
      int e = e0 + i;
      if (e < E) {
        int s = ei[e];
        if (s >= lo && s < hi) {
          int r = atomicAdd(&cnt[s], 1);
          if (r < CAP) {
            unsigned pk = ((unsigned)ei[E + e] << 15) | ((unsigned)f2bf(ew[e]) & 0x7fffu);
            recs[((size_t)s << 6) + r] = pk;
          }
        }
      }
    }
    return;
  }
  int w = threadIdx.x >> 6, l = threadIdx.x & 63;
  int n0 = (int)blockIdx.x * 64 + w * 16;
  int lr = l & 15, lg = l >> 4;

  short8 a[4];
  int arow = n0 + lr;
  if (arow < N) {
    const float* xrow = x + (size_t)arow * 128 + 8 * lg;
    float4 x0[4], x1[4];
#pragma unroll
    for (int ks = 0; ks < 4; ks++) {
      x0[ks] = *(const float4*)(xrow + 32 * ks);
      x1[ks] = *(const float4*)(xrow + 32 * ks + 4);
    }
#pragma unroll
    for (int ks = 0; ks < 4; ks++) {
      short8 t;
      t[0] = f2bf(x0[ks].x); t[1] = f2bf(x0[ks].y); t[2] = f2bf(x0[ks].z); t[3] = f2bf(x0[ks].w);
      t[4] = f2bf(x1[ks].x); t[5] = f2bf(x1[ks].y); t[6] = f2bf(x1[ks].z); t[7] = f2bf(x1[ks].w);
      a[ks] = t;
    }
  } else {
#pragma unroll
    for (int ks = 0; ks < 4; ks++) a[ks] = (short8){0,0,0,0,0,0,0,0};
  }

  bool ok[4];
#pragma unroll
  for (int r = 0; r < 4; r++) ok[r] = (n0 + 4 * lg + r) < N;

#pragma unroll
  for (int m = 0; m < 3; m++) {
    const ushort* Wm = Wb + m * 16384;
#pragma unroll
    for (int ctp = 0; ctp < 4; ctp++) {
      short8 b[2][4];
#pragma unroll
      for (int ci = 0; ci < 2; ci++) {
        const ushort* wrow = Wm + (size_t)((ctp * 2 + ci) * 16 + lr) * 128 + 8 * lg;
#pragma unroll
        for (int ks = 0; ks < 4; ks++) b[ci][ks] = *(const short8*)(wrow + 32 * ks);
      }
#pragma unroll
      for (int ci = 0; ci < 2; ci++) {
        f32x4 acc = {0.f, 0.f, 0.f, 0.f};
#pragma unroll
        for (int ks = 0; ks < 4; ks++)
          acc = __builtin_amdgcn_mfma_f32_16x16x32_bf16(a[ks], b[ci][ks], acc, 0, 0, 0);
        int c = (ctp * 2 + ci) * 16 + lr;
#pragma unroll
        for (int r = 0; r < 4; r++) {
          if (ok[r]) {
            size_t row = (size_t)(n0 + 4 * lg + r);
            if (m == 0)      Qf[row * 128 + c] = acc[r];
            else if (m == 1) KVb[row * 256 + c] = f2bf(acc[r]);
            else             KVb[row * 256 + 128 + c] = f2bf(acc[r]);
          }
        }
      }
    }
  }
}

// 4 waves/block, wave-per-node. Lane = (slot u = l>>3, head h = l&7).
// Bucket preloaded: lane l holds rb[min(l,deg-1)]; per-iter rec via shfl.
// Per-lane online softmax chain (defer-max THR=8); slot-merge via shfl_xor.
__global__ __launch_bounds__(256) void edge_attn_kernel(
    const float* __restrict__ Qf, const ushort* __restrict__ KVb,
    const unsigned* __restrict__ recs, const float* __restrict__ We,
    const int* __restrict__ cnt, ushort* __restrict__ AGGb, int N) {
  int wv = threadIdx.x >> 6, l = threadIdx.x & 63;
  int n = blockIdx.x * 4 + wv;
  if (n >= N) return;
  int u = l >> 3, h = l & 7;
  int deg = min(cnt[n], CAP);
  ushort* op = AGGb + (size_t)n * 128 + (h << 4);

  if (deg <= 0) {                    // no edges: agg = 0
    if (u == 0) {
      *(uint4*)(op + 0) = make_uint4(0, 0, 0, 0);
      *(uint4*)(op + 8) = make_uint4(0, 0, 0, 0);
    }
    return;
  }

  const unsigned* rb = recs + ((size_t)n << 6);
  unsigned myrec = rb[min(l, deg - 1)];          // coalesced bucket preload

  float q[16];
  const float* qp = Qf + (size_t)n * 128 + (h << 4);
  *(float4*)(q + 0)  = *(const float4*)(qp + 0);
  *(float4*)(q + 4)  = *(const float4*)(qp + 4);
  *(float4*)(q + 8)  = *(const float4*)(qp + 8);
  *(float4*)(q + 12) = *(const float4*)(qp + 12);
  float weh = We[h];

  float m = -INFINITY, de = 0.f;
  float acc[16];
#pragma unroll
  for (int d = 0; d < 16; d++) acc[d] = 0.f;

  for (int base = 0; base < deg; base += 8) {
    int idx = base + u;                          // <= 63
    unsigned rec = __shfl(myrec, idx);           // lanes >= deg hold rb[deg-1]
    const ushort* kv = KVb + (((rec >> 15) << 8) + (h << 4));
    uint4 k0 = *(const uint4*)kv;
    uint4 k1 = *(const uint4*)(kv + 8);
    uint4 v0 = *(const uint4*)(kv + 128);
    uint4 v1 = *(const uint4*)(kv + 136);

    float s;
    s  = q[0]  * bflo(k0.x) + q[1]  * bfhi(k0.x);
    s += q[2]  * bflo(k0.y) + q[3]  * bfhi(k0.y);
    s += q[4]  * bflo(k0.z) + q[5]  * bfhi(k0.z);
    s += q[6]  * bflo(k0.w) + q[7]  * bfhi(k0.w);
    s += q[8]  * bflo(k1.x) + q[9]  * bfhi(k1.x);
    s += q[10] * bflo(k1.y) + q[11] * bfhi(k1.y);
    s += q[12] * bflo(k1.z) + q[13] * bfhi(k1.z);
    s += q[14] * bflo(k1.w) + q[15] * bfhi(k1.w);
    s = s * 0.25f + __uint_as_float((rec & 0x7fffu) << 16) * weh;
    if (idx >= deg) s = -INFINITY;

    float p;
    if (s > m + 8.f) {               // first real edge always takes this path
      float c = __expf(m - s);       // exp(-inf)=0 on first edge
      de *= c;
#pragma unroll
      for (int d = 0; d < 16; d++) acc[d] *= c;
      m = s;
      p = 1.f;
    } else {
      p = __expf(s - m);             // bounded by e^8; NaN only on pad-only lanes
    }
    de += p;
    acc[0]  += p * bflo(v0.x); acc[1]  += p * bfhi(v0.x);
    acc[2]  += p * bflo(v0.y); acc[3]  += p * bfhi(v0.y);
    acc[4]  += p * bflo(v0.z); acc[5]  += p * bfhi(v0.z);
    acc[6]  += p * bflo(v0.w); acc[7]  += p * bfhi(v0.w);
    acc[8]  += p * bflo(v1.x); acc[9]  += p * bfhi(v1.x);
    acc[10] += p * bflo(v1.y); acc[11] += p * bfhi(v1.y);
    acc[12] += p * bflo(v1.z); acc[13] += p * bfhi(v1.z);
    acc[14] += p * bflo(v1.w); acc[15] += p * bfhi(v1.w);
  }

  // pad-only lanes (u >= deg): m stayed -inf, de/acc are NaN -> zero them
  bool live = (m > -INFINITY);
  if (!live) {
    de = 0.f;
#pragma unroll
    for (int d = 0; d < 16; d++) acc[d] = 0.f;
  }
  // merge 8 slot-chains per head: lanes {h, h+8, ..., h+56}
  float M = m;
  M = fmaxf(M, __shfl_xor(M, 8));
  M = fmaxf(M, __shfl_xor(M, 16));
  M = fmaxf(M, __shfl_xor(M, 32));
  float c = live ? __expf(m - M) : 0.f;
  de *= c;
#pragma unroll
  for (int d = 0; d < 16; d++) acc[d] *= c;
  de += __shfl_xor(de, 8); de += __shfl_xor(de, 16); de += __shfl_xor(de, 32);
#pragma unroll
  for (int d = 0; d < 16; d++) {
    acc[d] += __shfl_xor(acc[d], 8);
    acc[d] += __shfl_xor(acc[d], 16);
    acc[d] += __shfl_xor(acc[d], 32);
  }

  if (u == 0) {
    float inv = (de > 0.f) ? 1.0f / de : 0.f;
    unsigned o[8];
#pragma unroll
    for (int j = 0; j < 8; j++) {
      ushort lo = f2bf(acc[2 * j] * inv);
      ushort hi = f2bf(acc[2 * j + 1] * inv);
      o[j] = (unsigned)lo | ((unsigned)hi << 16);
    }
    *(uint4*)(op + 0) = make_uint4(o[0], o[1], o[2], o[3]);
    *(uint4*)(op + 8) = make_uint4(o[4], o[5], o[6], o[7]);
  }
}

// Wo GEMM (bf16 MFMA, batched B-loads) + residual + LayerNorm fused.
__global__ __launch_bounds__(256) void wo_ln_kernel(
    const ushort* __restrict__ AGGb, const ushort* __restrict__ Wob,
    const float* __restrict__ x, const float* __restrict__ gamma,
    const float* __restrict__ beta, float* __restrict__ out, int N) {
  int w = threadIdx.x >> 6, l = threadIdx.x & 63;
  int n0 = blockIdx.x * 64 + w * 16;
  int lr = l & 15, lg = l >> 4;
  short8 a[4];
  const ushort* arow = AGGb + (size_t)(n0 + lr) * 128 + 8 * lg;
#pragma unroll
  for (int ks = 0; ks < 4; ks++) a[ks] = *(const short8*)(arow + 32 * ks);

  f32x4 acc[8];
#pragma unroll
  for (int ctp = 0; ctp < 4; ctp++) {
    short8 b[2][4];
#pragma unroll
    for (int ci = 0; ci < 2; ci++) {
      const ushort* wrow = Wob + (size_t)((ctp * 2 + ci) * 16 + lr) * 128 + 8 * lg;
#pragma unroll
      for (int ks = 0; ks < 4; ks++) b[ci][ks] = *(const short8*)(wrow + 32 * ks);
    }
#pragma unroll
    for (int ci = 0; ci < 2; ci++) {
      int ct = ctp * 2 + ci;
      acc[ct] = (f32x4){0.f, 0.f, 0.f, 0.f};
#pragma unroll
      for (int ks = 0; ks < 4; ks++)
        acc[ct] = __builtin_amdgcn_mfma_f32_16x16x32_bf16(a[ks], b[ci][ks], acc[ct], 0, 0, 0);
    }
  }
  float g[8], bt[8];
#pragma unroll
  for (int ct = 0; ct < 8; ct++) { g[ct] = gamma[ct * 16 + lr]; bt[ct] = beta[ct * 16 + lr]; }

#pragma unroll
  for (int r = 0; r < 4; r++) {
    int row = n0 + 4 * lg + r;
    bool ok = row < N;
    float v[8], s = 0.f, s2 = 0.f;
#pragma unroll
    for (int ct = 0; ct < 8; ct++) {
      float xv = ok ? x[(size_t)row * 128 + ct * 16 + lr] : 0.f;
      v[ct] = acc[ct][r] + xv;
      s += v[ct]; s2 += v[ct] * v[ct];
    }
#pragma unroll
    for (int d = 1; d < 16; d <<= 1) { s += __shfl_xor(s, d); s2 += __shfl_xor(s2, d); }
    float mu = s * (1.f / 128.f);
    float var = s2 * (1.f / 128.f) - mu * mu;
    float rs = rsqrtf(var + 1e-5f);
    if (ok) {
#pragma unroll
      for (int ct = 0; ct < 8; ct++)
        out[(size_t)row * 128 + ct * 16 + lr] = (v[ct] - mu) * rs * g[ct] + bt[ct];
    }
  }
}

extern "C" void kernel_launch(void* const* d_in, const int* in_sizes, int n_in,
                              void* d_out, int out_size, void* d_ws, size_t ws_size,
                              hipStream_t stream) {
  const float* x     = (const float*)d_in[0];
  const int*   ei    = (const int*)d_in[1];
  const float* ew    = (const float*)d_in[2];
  const float* Wq    = (const float*)d_in[3];
  const float* Wk    = (const float*)d_in[4];
  const float* Wv    = (const float*)d_in[5];
  const float* We    = (const float*)d_in[6];
  const float* Wo    = (const float*)d_in[7];
  const float* gamma = (const float*)d_in[8];
  const float* beta  = (const float*)d_in[9];

  int N = in_sizes[0] / 128;
  int E = in_sizes[1] / 2;
  int Npad = (N + 127) & ~127;
  int QB = Npad / 64;                    // 782 GEMM blocks (1 tile/wave)
  int SB = 8 * ((E + 2047) / 2048 / 1 + ((E % 2048) ? 0 : 0));  // see below
  SB = 8 * ((E + 2047) / 2048);          // 8 groups x 391 chunk-blocks

  char* ws = (char*)d_ws;
  ushort* Wb   = (ushort*)ws; ws += 4 * 16384 * 2;          // [Wq,Wk,Wv,Wo] bf16
  float*  Qf   = (float*)ws;  ws += (size_t)Npad * 128 * 4;
  ushort* KVb  = (ushort*)ws; ws += (size_t)Npad * 256 * 2; // [K row | V row]
  ushort* AGGb = (ushort*)ws; ws += (size_t)Npad * 128 * 2;
  int* cnt  = (int*)ws; ws += (size_t)N * 4;
  unsigned* recs = (unsigned*)ws; ws += (size_t)N * CAP * 4;
  ushort* Wob = Wb + 3 * 16384;

  hipMemsetAsync(cnt, 0, (size_t)N * 4, stream);

  prep_kernel<<<64, 256, 0, stream>>>(Wq, Wk, Wv, Wo, Wb);

  qkv_histfill_kernel<<<QB + SB, 256, 0, stream>>>(x, Wb, Qf, KVb, ei, ew, cnt, recs, N, E, QB);

  edge_attn_kernel<<<(N + 3) / 4, 256, 0, stream>>>(Qf, KVb, recs, We, cnt, AGGb, N);

  wo_ln_kernel<<<Npad / 64, 256, 0, stream>>>(AGGb, Wob, x, gamma, beta, (float*)d_out, N);
}

// Round 13
// 147.757 us; speedup vs baseline: 1.2553x; 1.1082x over previous
//
#include <hip/hip_runtime.h>
#include <hip/hip_bf16.h>
#include <math.h>

// ---------------------------------------------------------------------------
// EdgeAwareAttention: B=1, N=50000, D=128, H=8, d=16, E=800000
//  prep         : Wq,Wk,Wv,Wo f32->bf16
//  qkv_histfill : [blocks 0..QB)  MFMA QKV, 4 row-tiles/wave (B-frag reuse x4)
//                 [blocks QB..)   XCD-partitioned bucket scatter (group=sb&7,
//                                 src-range filter, 8 edges/thread)
//  edge_attn    : 4 waves/block, wave-per-node, bucket preload + shfl,
//                 lane=(slot,head), defer-max, slot-merge via shfl_xor
//  wo_ln        : MFMA Wo GEMM, 2 row-tiles/wave + residual + LayerNorm
// Bucket capacity 64: deg~Poisson(16), P(deg>64)~1e-26; r<64 clamp = safe.
// ---------------------------------------------------------------------------

#define CAP 64

typedef __attribute__((ext_vector_type(8))) short short8;
typedef __attribute__((ext_vector_type(4))) float f32x4;

static __device__ __forceinline__ ushort f2bf(float f) {
  unsigned u = __float_as_uint(f);
  u += 0x7fff + ((u >> 16) & 1);          // RNE
  return (ushort)(u >> 16);
}
static __device__ __forceinline__ float bflo(unsigned u) {   // low bf16 -> f32
  return __uint_as_float(u << 16);
}
static __device__ __forceinline__ float bfhi(unsigned u) {   // high bf16 -> f32
  return __uint_as_float(u & 0xffff0000u);
}

// W convert (4*16384 f32 -> bf16)
__global__ __launch_bounds__(256) void prep_kernel(
    const float* __restrict__ Wq, const float* __restrict__ Wk,
    const float* __restrict__ Wv, const float* __restrict__ Wo,
    ushort* __restrict__ Wb) {
  int tid = blockIdx.x * 256 + threadIdx.x;
  if (tid < 16384) {
    int i = tid * 4;
    const float* src = (i < 16384) ? Wq : (i < 32768) ? Wk : (i < 49152) ? Wv : Wo;
    int off = i & 16383;
    float4 v = *(const float4*)(src + off);
    *(ushort4*)(Wb + i) = make_ushort4(f2bf(v.x), f2bf(v.y), f2bf(v.z), f2bf(v.w));
  }
}

// Fused: QKV MFMA GEMM (blocks < QB) | XCD-partitioned scatter (blocks >= QB).
// GEMM: wave = 64 rows = 4 tiles of 16; B-frags loaded once per (m,ctp) and
// reused across the 4 A-tiles (3.25x fewer load-waits than 1-tile).
// Scatter: group p=sb&7 handles src in [N*p/8, N*(p+1)/8) (cnt slice L2-local).
// KVb layout: row n = [K[0..128) | V[0..128)] (256 ushorts).
__global__ __launch_bounds__(256) void qkv_histfill_kernel(
    const float* __restrict__ x, const ushort* __restrict__ Wb,   // Wb: [3][128][128]
    float* __restrict__ Qf, ushort* __restrict__ KVb,
    const int* __restrict__ ei, const float* __restrict__ ew,
    int* __restrict__ cnt, unsigned* __restrict__ recs,
    int N, int E, int QB) {
  if ((int)blockIdx.x >= QB) {
    int sb = (int)blockIdx.x - QB;
    int p  = sb & 7;                     // XCD group (round-robin heuristic)
    int k  = sb >> 3;
    int lo = (int)((long)N * p >> 3);
    int hi = (int)((long)N * (p + 1) >> 3);
    int e0 = k * 2048 + (int)threadIdx.x * 8;
#pragma unroll
    for (int i = 0; i < 8; i++) {
      int e = e0 + i;
      if (e < E) {
        int s = ei[e];
        if (s >= lo && s < hi) {
          int r = atomicAdd(&cnt[s], 1);
          if (r < CAP) {
            unsigned pk = ((unsigned)ei[E + e] << 15) | ((unsigned)f2bf(ew[e]) & 0x7fffu);
            recs[((size_t)s << 6) + r] = pk;
          }
        }
      }
    }
    return;
  }
  int w = threadIdx.x >> 6, l = threadIdx.x & 63;
  int n0 = (int)blockIdx.x * 256 + w * 64;   // wave: 64 rows = 4 tiles
  int lr = l & 15, lg = l >> 4;

  short8 a[4][4];
#pragma unroll
  for (int rt = 0; rt < 4; rt++) {
    int arow = n0 + rt * 16 + lr;
    if (arow < N) {
      const float* xrow = x + (size_t)arow * 128 + 8 * lg;
      float4 x0[4], x1[4];
#pragma unroll
      for (int ks = 0; ks < 4; ks++) {
        x0[ks] = *(const float4*)(xrow + 32 * ks);
        x1[ks] = *(const float4*)(xrow + 32 * ks + 4);
      }
#pragma unroll
      for (int ks = 0; ks < 4; ks++) {
        short8 t;
        t[0] = f2bf(x0[ks].x); t[1] = f2bf(x0[ks].y); t[2] = f2bf(x0[ks].z); t[3] = f2bf(x0[ks].w);
        t[4] = f2bf(x1[ks].x); t[5] = f2bf(x1[ks].y); t[6] = f2bf(x1[ks].z); t[7] = f2bf(x1[ks].w);
        a[rt][ks] = t;
      }
    } else {
#pragma unroll
      for (int ks = 0; ks < 4; ks++) a[rt][ks] = (short8){0,0,0,0,0,0,0,0};
    }
  }

#pragma unroll
  for (int m = 0; m < 3; m++) {
    const ushort* Wm = Wb + m * 16384;
#pragma unroll
    for (int ctp = 0; ctp < 4; ctp++) {
      short8 b[2][4];
#pragma unroll
      for (int ci = 0; ci < 2; ci++) {
        const ushort* wrow = Wm + (size_t)((ctp * 2 + ci) * 16 + lr) * 128 + 8 * lg;
#pragma unroll
        for (int ks = 0; ks < 4; ks++) b[ci][ks] = *(const short8*)(wrow + 32 * ks);
      }
#pragma unroll
      for (int rt = 0; rt < 4; rt++) {
#pragma unroll
        for (int ci = 0; ci < 2; ci++) {
          f32x4 acc = {0.f, 0.f, 0.f, 0.f};
#pragma unroll
          for (int ks = 0; ks < 4; ks++)
            acc = __builtin_amdgcn_mfma_f32_16x16x32_bf16(a[rt][ks], b[ci][ks], acc, 0, 0, 0);
          int c = (ctp * 2 + ci) * 16 + lr;
#pragma unroll
          for (int r = 0; r < 4; r++) {
            int row = n0 + rt * 16 + 4 * lg + r;
            if (row < N) {
              if (m == 0)      Qf[(size_t)row * 128 + c] = acc[r];
              else if (m == 1) KVb[(size_t)row * 256 + c] = f2bf(acc[r]);
              else             KVb[(size_t)row * 256 + 128 + c] = f2bf(acc[r]);
            }
          }
        }
      }
    }
  }
}

// 4 waves/block, wave-per-node. Lane = (slot u = l>>3, head h = l&7).
// Bucket preloaded: lane l holds rb[min(l,deg-1)]; per-iter rec via shfl.
// Per-lane online softmax chain (defer-max THR=8); slot-merge via shfl_xor.
__global__ __launch_bounds__(256) void edge_attn_kernel(
    const float* __restrict__ Qf, const ushort* __restrict__ KVb,
    const unsigned* __restrict__ recs, const float* __restrict__ We,
    const int* __restrict__ cnt, ushort* __restrict__ AGGb, int N) {
  int wv = threadIdx.x >> 6, l = threadIdx.x & 63;
  int n = blockIdx.x * 4 + wv;
  if (n >= N) return;
  int u = l >> 3, h = l & 7;
  int deg = min(cnt[n], CAP);
  ushort* op = AGGb + (size_t)n * 128 + (h << 4);

  if (deg <= 0) {                    // no edges: agg = 0
    if (u == 0) {
      *(uint4*)(op + 0) = make_uint4(0, 0, 0, 0);
      *(uint4*)(op + 8) = make_uint4(0, 0, 0, 0);
    }
    return;
  }

  const unsigned* rb = recs + ((size_t)n << 6);
  unsigned myrec = rb[min(l, deg - 1)];          // coalesced bucket preload

  float q[16];
  const float* qp = Qf + (size_t)n * 128 + (h << 4);
  *(float4*)(q + 0)  = *(const float4*)(qp + 0);
  *(float4*)(q + 4)  = *(const float4*)(qp + 4);
  *(float4*)(q + 8)  = *(const float4*)(qp + 8);
  *(float4*)(q + 12) = *(const float4*)(qp + 12);
  float weh = We[h];

  float m = -INFINITY, de = 0.f;
  float acc[16];
#pragma unroll
  for (int d = 0; d < 16; d++) acc[d] = 0.f;

  for (int base = 0; base < deg; base += 8) {
    int idx = base + u;                          // <= 63
    unsigned rec = __shfl(myrec, idx);           // lanes >= deg hold rb[deg-1]
    const ushort* kv = KVb + (((rec >> 15) << 8) + (h << 4));
    uint4 k0 = *(const uint4*)kv;
    uint4 k1 = *(const uint4*)(kv + 8);
    uint4 v0 = *(const uint4*)(kv + 128);
    uint4 v1 = *(const uint4*)(kv + 136);

    float s;
    s  = q[0]  * bflo(k0.x) + q[1]  * bfhi(k0.x);
    s += q[2]  * bflo(k0.y) + q[3]  * bfhi(k0.y);
    s += q[4]  * bflo(k0.z) + q[5]  * bfhi(k0.z);
    s += q[6]  * bflo(k0.w) + q[7]  * bfhi(k0.w);
    s += q[8]  * bflo(k1.x) + q[9]  * bfhi(k1.x);
    s += q[10] * bflo(k1.y) + q[11] * bfhi(k1.y);
    s += q[12] * bflo(k1.z) + q[13] * bfhi(k1.z);
    s += q[14] * bflo(k1.w) + q[15] * bfhi(k1.w);
    s = s * 0.25f + __uint_as_float((rec & 0x7fffu) << 16) * weh;
    if (idx >= deg) s = -INFINITY;

    float p;
    if (s > m + 8.f) {               // first real edge always takes this path
      float c = __expf(m - s);       // exp(-inf)=0 on first edge
      de *= c;
#pragma unroll
      for (int d = 0; d < 16; d++) acc[d] *= c;
      m = s;
      p = 1.f;
    } else {
      p = __expf(s - m);             // bounded by e^8; NaN only on pad-only lanes
    }
    de += p;
    acc[0]  += p * bflo(v0.x); acc[1]  += p * bfhi(v0.x);
    acc[2]  += p * bflo(v0.y); acc[3]  += p * bfhi(v0.y);
    acc[4]  += p * bflo(v0.z); acc[5]  += p * bfhi(v0.z);
    acc[6]  += p * bflo(v0.w); acc[7]  += p * bfhi(v0.w);
    acc[8]  += p * bflo(v1.x); acc[9]  += p * bfhi(v1.x);
    acc[10] += p * bflo(v1.y); acc[11] += p * bfhi(v1.y);
    acc[12] += p * bflo(v1.z); acc[13] += p * bfhi(v1.z);
    acc[14] += p * bflo(v1.w); acc[15] += p * bfhi(v1.w);
  }

  // pad-only lanes (u >= deg): m stayed -inf, de/acc are NaN -> zero them
  bool live = (m > -INFINITY);
  if (!live) {
    de = 0.f;
#pragma unroll
    for (int d = 0; d < 16; d++) acc[d] = 0.f;
  }
  // merge 8 slot-chains per head: lanes {h, h+8, ..., h+56}
  float M = m;
  M = fmaxf(M, __shfl_xor(M, 8));
  M = fmaxf(M, __shfl_xor(M, 16));
  M = fmaxf(M, __shfl_xor(M, 32));
  float c = live ? __expf(m - M) : 0.f;
  de *= c;
#pragma unroll
  for (int d = 0; d < 16; d++) acc[d] *= c;
  de += __shfl_xor(de, 8); de += __shfl_xor(de, 16); de += __shfl_xor(de, 32);
#pragma unroll
  for (int d = 0; d < 16; d++) {
    acc[d] += __shfl_xor(acc[d], 8);
    acc[d] += __shfl_xor(acc[d], 16);
    acc[d] += __shfl_xor(acc[d], 32);
  }

  if (u == 0) {
    float inv = (de > 0.f) ? 1.0f / de : 0.f;
    unsigned o[8];
#pragma unroll
    for (int j = 0; j < 8; j++) {
      ushort lo = f2bf(acc[2 * j] * inv);
      ushort hi = f2bf(acc[2 * j + 1] * inv);
      o[j] = (unsigned)lo | ((unsigned)hi << 16);
    }
    *(uint4*)(op + 0) = make_uint4(o[0], o[1], o[2], o[3]);
    *(uint4*)(op + 8) = make_uint4(o[4], o[5], o[6], o[7]);
  }
}

// Wo GEMM (bf16 MFMA), 2 row-tiles/wave (B-frag reuse x2) + residual + LN.
__global__ __launch_bounds__(256) void wo_ln_kernel(
    const ushort* __restrict__ AGGb, const ushort* __restrict__ Wob,
    const float* __restrict__ x, const float* __restrict__ gamma,
    const float* __restrict__ beta, float* __restrict__ out, int N) {
  int w = threadIdx.x >> 6, l = threadIdx.x & 63;
  int n0 = blockIdx.x * 128 + w * 32;       // wave: 32 rows = 2 tiles
  int lr = l & 15, lg = l >> 4;

  short8 a[2][4];
#pragma unroll
  for (int rt = 0; rt < 2; rt++) {
    int arow = n0 + rt * 16 + lr;
    if (arow < N) {
      const ushort* ap = AGGb + (size_t)arow * 128 + 8 * lg;
#pragma unroll
      for (int ks = 0; ks < 4; ks++) a[rt][ks] = *(const short8*)(ap + 32 * ks);
    } else {
#pragma unroll
      for (int ks = 0; ks < 4; ks++) a[rt][ks] = (short8){0,0,0,0,0,0,0,0};
    }
  }

  f32x4 acc[2][8];
#pragma unroll
  for (int ctp = 0; ctp < 4; ctp++) {
    short8 b[2][4];
#pragma unroll
    for (int ci = 0; ci < 2; ci++) {
      const ushort* wrow = Wob + (size_t)((ctp * 2 + ci) * 16 + lr) * 128 + 8 * lg;
#pragma unroll
      for (int ks = 0; ks < 4; ks++) b[ci][ks] = *(const short8*)(wrow + 32 * ks);
    }
#pragma unroll
    for (int rt = 0; rt < 2; rt++)
#pragma unroll
      for (int ci = 0; ci < 2; ci++) {
        int ct = ctp * 2 + ci;
        acc[rt][ct] = (f32x4){0.f, 0.f, 0.f, 0.f};
#pragma unroll
        for (int ks = 0; ks < 4; ks++)
          acc[rt][ct] = __builtin_amdgcn_mfma_f32_16x16x32_bf16(a[rt][ks], b[ci][ks], acc[rt][ct], 0, 0, 0);
      }
  }
  float g[8], bt[8];
#pragma unroll
  for (int ct = 0; ct < 8; ct++) { g[ct] = gamma[ct * 16 + lr]; bt[ct] = beta[ct * 16 + lr]; }

#pragma unroll
  for (int rt = 0; rt < 2; rt++) {
#pragma unroll
    for (int r = 0; r < 4; r++) {
      int row = n0 + rt * 16 + 4 * lg + r;
      bool ok = row < N;
      float v[8], s = 0.f, s2 = 0.f;
#pragma unroll
      for (int ct = 0; ct < 8; ct++) {
        float xv = ok ? x[(size_t)row * 128 + ct * 16 + lr] : 0.f;
        v[ct] = acc[rt][ct][r] + xv;
        s += v[ct]; s2 += v[ct] * v[ct];
      }
#pragma unroll
      for (int d = 1; d < 16; d <<= 1) { s += __shfl_xor(s, d); s2 += __shfl_xor(s2, d); }
      float mu = s * (1.f / 128.f);
      float var = s2 * (1.f / 128.f) - mu * mu;
      float rs = rsqrtf(var + 1e-5f);
      if (ok) {
#pragma unroll
        for (int ct = 0; ct < 8; ct++)
          out[(size_t)row * 128 + ct * 16 + lr] = (v[ct] - mu) * rs * g[ct] + bt[ct];
      }
    }
  }
}

extern "C" void kernel_launch(void* const* d_in, const int* in_sizes, int n_in,
                              void* d_out, int out_size, void* d_ws, size_t ws_size,
                              hipStream_t stream) {
  const float* x     = (const float*)d_in[0];
  const int*   ei    = (const int*)d_in[1];
  const float* ew    = (const float*)d_in[2];
  const float* Wq    = (const float*)d_in[3];
  const float* Wk    = (const float*)d_in[4];
  const float* Wv    = (const float*)d_in[5];
  const float* We    = (const float*)d_in[6];
  const float* Wo    = (const float*)d_in[7];
  const float* gamma = (const float*)d_in[8];
  const float* beta  = (const float*)d_in[9];

  int N = in_sizes[0] / 128;
  int E = in_sizes[1] / 2;
  int Npad = (N + 255) & ~255;
  int QB = Npad / 256;                   // 196 GEMM blocks (4 tiles/wave)
  int SB = 8 * ((E + 2047) / 2048);      // 8 groups x 391 chunk-blocks

  char* ws = (char*)d_ws;
  ushort* Wb   = (ushort*)ws; ws += 4 * 16384 * 2;          // [Wq,Wk,Wv,Wo] bf16
  float*  Qf   = (float*)ws;  ws += (size_t)Npad * 128 * 4;
  ushort* KVb  = (ushort*)ws; ws += (size_t)Npad * 256 * 2; // [K row | V row]
  ushort* AGGb = (ushort*)ws; ws += (size_t)Npad * 128 * 2;
  int* cnt  = (int*)ws; ws += (size_t)N * 4;
  unsigned* recs = (unsigned*)ws; ws += (size_t)N * CAP * 4;
  ushort* Wob = Wb + 3 * 16384;

  hipMemsetAsync(cnt, 0, (size_t)N * 4, stream);

  prep_kernel<<<64, 256, 0, stream>>>(Wq, Wk, Wv, Wo, Wb);

  qkv_histfill_kernel<<<QB + SB, 256, 0, stream>>>(x, Wb, Qf, KVb, ei, ew, cnt, recs, N, E, QB);

  edge_attn_kernel<<<(N + 3) / 4, 256, 0, stream>>>(Qf, KVb, recs, We, cnt, AGGb, N);

  wo_ln_kernel<<<Npad / 128, 256, 0, stream>>>(AGGb, Wob, x, gamma, beta, (float*)d_out, N);
}